// Round 2
// baseline (253.441 us; speedup 1.0000x reference)
//
#include <hip/hip_runtime.h>
#include <math.h>

#define B_   2
#define C_   256
#define C4_  64
#define H_   128
#define W_   128
#define HW_  (H_*W_)
#define G_   4

// ---------------------------------------------------------------------------
// Kernel 1: fold W0 + BN + W1 into a single 4x256 matrix + 4-vector.
// logits[g] = sum_c Weff[g][c]*feat[c] + beff[g]
// ---------------------------------------------------------------------------
__global__ __launch_bounds__(256) void prep_kernel(
    const float* __restrict__ W0, const float* __restrict__ b0,
    const float* __restrict__ gamma, const float* __restrict__ beta,
    const float* __restrict__ rmean, const float* __restrict__ rvar,
    const float* __restrict__ W1, const float* __restrict__ b1,
    float* __restrict__ Weff, float* __restrict__ beff)
{
    int t = threadIdx.x;   // 0..255 -> c
    #pragma unroll
    for (int g = 0; g < G_; ++g) {
        float s = 0.f;
        for (int o = 0; o < C4_; ++o) {
            float inv = gamma[o] * rsqrtf(rvar[o] + 1e-5f);
            s += W1[g*C4_ + o] * inv * W0[o*C_ + t];
        }
        Weff[g*C_ + t] = s;
    }
    if (t < G_) {
        float s = b1[t];
        for (int o = 0; o < C4_; ++o) {
            float inv = gamma[o] * rsqrtf(rvar[o] + 1e-5f);
            s += W1[t*C4_ + o] * ((b0[o] - rmean[o]) * inv + beta[o]);
        }
        beff[t] = s;
    }
}

// ---------------------------------------------------------------------------
// Kernel 2: transpose x (B,C,HW) -> xT (B,HW,C).  xT lives in d_out (same
// byte size); ws only holds the small att buffer.
// ---------------------------------------------------------------------------
__global__ __launch_bounds__(256) void transpose_kernel(
    const float* __restrict__ x, float* __restrict__ xT)
{
    __shared__ float tile[32][33];
    int tx = threadIdx.x, ty = threadIdx.y;
    int hw0 = blockIdx.x * 32, c0 = blockIdx.y * 32, b = blockIdx.z;
    const float* xb  = x  + (size_t)b * C_ * HW_;
    float*       xTb = xT + (size_t)b * C_ * HW_;
    #pragma unroll
    for (int j = 0; j < 4; ++j)
        tile[ty + 8*j][tx] = xb[(size_t)(c0 + ty + 8*j) * HW_ + hw0 + tx];
    __syncthreads();
    #pragma unroll
    for (int j = 0; j < 4; ++j)
        xTb[(size_t)(hw0 + ty + 8*j) * C_ + c0 + tx] = tile[tx][ty + 8*j];
}

// ---------------------------------------------------------------------------
// Kernel 3: deformable 3x3 unfold + bilinear + max over taps + 4x256 dot +
// sigmoid.  One wave per pixel-iteration; lane l owns channels [4l, 4l+4).
// Block: 512 threads (8 waves) covers 64 consecutive x of one row.
// Offsets for the 64 pixels are staged through LDS (coalesced once, then
// broadcast-read) instead of 18 wave-uniform global loads per pixel.
// ---------------------------------------------------------------------------
__global__ __launch_bounds__(512, 4) void main_kernel(
    const float* __restrict__ xT, const float* __restrict__ offset,
    const float* __restrict__ Weff, const float* __restrict__ beff,
    float* __restrict__ att)
{
    __shared__ float offs_lds[18][64];
    __shared__ float att_lds[G_ * 64];
    int t = threadIdx.x;
    int wave = t >> 6, lane = t & 63;
    int bid = blockIdx.x;
    int xh = bid & 1;                 // W/64 = 2 chunks
    int y  = (bid >> 1) & (H_ - 1);
    int b  = bid >> 8;
    int x0 = xh * 64;
    int c0 = lane * 4;

    const float* xTb  = xT + (size_t)b * HW_ * C_;
    const float* offb = offset + (size_t)b * 18 * HW_ + (size_t)y * W_ + x0;

    // cooperative coalesced load of the 18x64 offset slab
    for (int idx = t; idx < 18 * 64; idx += 512)
        offs_lds[idx >> 6][idx & 63] = offb[(size_t)(idx >> 6) * HW_ + (idx & 63)];

    // per-lane Weff fragment (16 regs) + beff
    float wf[G_][4];
    #pragma unroll
    for (int g = 0; g < G_; ++g) {
        float4 v = *(const float4*)(Weff + g*C_ + c0);
        wf[g][0] = v.x; wf[g][1] = v.y; wf[g][2] = v.z; wf[g][3] = v.w;
    }
    float be[G_];
    #pragma unroll
    for (int g = 0; g < G_; ++g) be[g] = beff[g];

    __syncthreads();

    for (int i = 0; i < 8; ++i) {
        int xl = wave * 8 + i;
        int x  = x0 + xl;
        float fm0 = -3.4028235e38f, fm1 = fm0, fm2 = fm0, fm3 = fm0;

        #pragma unroll
        for (int k = 0; k < 9; ++k) {
            float oy = offs_lds[2*k    ][xl];
            float ox = offs_lds[2*k + 1][xl];
            float py = (float)(y + (k/3) - 1) + oy;
            float px = (float)(x + (k%3) - 1) + ox;
            float y0f = floorf(py), x0f = floorf(px);
            float fy = py - y0f, fx = px - x0f;
            float vy0 = (y0f >=  0.f && y0f <= 127.f) ? 1.f : 0.f;
            float vy1 = (y0f >= -1.f && y0f <= 126.f) ? 1.f : 0.f;
            float vx0 = (x0f >=  0.f && x0f <= 127.f) ? 1.f : 0.f;
            float vx1 = (x0f >= -1.f && x0f <= 126.f) ? 1.f : 0.f;
            float wy0 = (1.f - fy) * vy0, wy1 = fy * vy1;
            float wx0 = (1.f - fx) * vx0, wx1 = fx * vx1;
            int iy0 = min(max((int)y0f,     0), H_-1);
            int iy1 = min(max((int)y0f + 1, 0), H_-1);
            int ix0 = min(max((int)x0f,     0), W_-1);
            int ix1 = min(max((int)x0f + 1, 0), W_-1);
            const float4 v00 = *(const float4*)(xTb + (((size_t)iy0*W_ + ix0) << 8) + c0);
            const float4 v01 = *(const float4*)(xTb + (((size_t)iy0*W_ + ix1) << 8) + c0);
            const float4 v10 = *(const float4*)(xTb + (((size_t)iy1*W_ + ix0) << 8) + c0);
            const float4 v11 = *(const float4*)(xTb + (((size_t)iy1*W_ + ix1) << 8) + c0);
            float w00 = wy0*wx0, w01 = wy0*wx1, w10 = wy1*wx0, w11 = wy1*wx1;
            float a0 = w00*v00.x + w01*v01.x + w10*v10.x + w11*v11.x;
            float a1 = w00*v00.y + w01*v01.y + w10*v10.y + w11*v11.y;
            float a2 = w00*v00.z + w01*v01.z + w10*v10.z + w11*v11.z;
            float a3 = w00*v00.w + w01*v01.w + w10*v10.w + w11*v11.w;
            fm0 = fmaxf(fm0, a0);
            fm1 = fmaxf(fm1, a1);
            fm2 = fmaxf(fm2, a2);
            fm3 = fmaxf(fm3, a3);
        }

        float p[G_];
        #pragma unroll
        for (int g = 0; g < G_; ++g)
            p[g] = wf[g][0]*fm0 + wf[g][1]*fm1 + wf[g][2]*fm2 + wf[g][3]*fm3;

        #pragma unroll
        for (int off2 = 32; off2 > 0; off2 >>= 1) {
            #pragma unroll
            for (int g = 0; g < G_; ++g)
                p[g] += __shfl_xor(p[g], off2);
        }

        if (lane == 0) {
            #pragma unroll
            for (int g = 0; g < G_; ++g)
                att_lds[g*64 + xl] = 1.f / (1.f + expf(-(p[g] + be[g])));
        }
    }
    __syncthreads();

    // coalesced store of this row-chunk of att (B,4,H,W)
    if (t < G_ * 64) {
        int g  = t >> 6;
        int xw = t & 63;
        att[((size_t)(b*G_ + g) * HW_) + y*W_ + x0 + xw] = att_lds[g*64 + xw];
    }
}

// ---------------------------------------------------------------------------
// Kernel 4: tile att (B,4,H,W) -> out (B,256,H,W), float4 coalesced.
// ---------------------------------------------------------------------------
__global__ __launch_bounds__(256) void expand_kernel(
    const float* __restrict__ att, float* __restrict__ out)
{
    int e4 = blockIdx.x * 256 + threadIdx.x;   // float4 index over out
    int x4 = e4 & 31;
    int y  = (e4 >> 5) & (H_ - 1);
    int c  = (e4 >> 12) & (C_ - 1);
    int b  = (e4 >> 20) & 1;
    float4 v = *(const float4*)(att + ((size_t)(b*G_ + (c & 3)) * HW_) + y*W_ + x4*4);
    *(float4*)(out + ((size_t)(b*C_ + c) * HW_) + y*W_ + x4*4) = v;
}

// ---------------------------------------------------------------------------
extern "C" void kernel_launch(void* const* d_in, const int* in_sizes, int n_in,
                              void* d_out, int out_size, void* d_ws, size_t ws_size,
                              hipStream_t stream)
{
    (void)in_sizes; (void)n_in; (void)out_size; (void)ws_size;
    const float* x      = (const float*)d_in[0];
    const float* offset = (const float*)d_in[1];
    const float* W0     = (const float*)d_in[2];
    const float* b0     = (const float*)d_in[3];
    const float* gamma  = (const float*)d_in[4];
    const float* beta   = (const float*)d_in[5];
    const float* rmean  = (const float*)d_in[6];
    const float* rvar   = (const float*)d_in[7];
    const float* W1     = (const float*)d_in[8];
    const float* b1     = (const float*)d_in[9];
    float* out = (float*)d_out;

    // xT reuses d_out (same byte size as x).  ws: att + Weff + beff (~530 KB).
    float* xT   = out;
    float* att  = (float*)d_ws;                       // B*4*HW floats
    float* Weff = att + (size_t)B_ * G_ * HW_;        // 1024 floats
    float* beff = Weff + G_ * C_;                     // 4 floats

    prep_kernel<<<dim3(1), dim3(256), 0, stream>>>(
        W0, b0, gamma, beta, rmean, rvar, W1, b1, Weff, beff);

    transpose_kernel<<<dim3(HW_/32, C_/32, B_), dim3(32, 8), 0, stream>>>(x, xT);

    main_kernel<<<dim3(B_ * H_ * (W_/64)), dim3(512), 0, stream>>>(
        xT, offset, Weff, beff, att);

    expand_kernel<<<dim3((B_*C_*HW_/4) / 256), dim3(256), 0, stream>>>(att, out);
}

// Round 3
// 170.968 us; speedup vs baseline: 1.4824x; 1.4824x over previous
//
#include <hip/hip_runtime.h>
#include <math.h>

#define B_   2
#define C_   256
#define C4_  64
#define H_   128
#define W_   128
#define HW_  (H_*W_)
#define G_   4
#define PX_  16                       // pixels per block
#define NCH_ (W_/PX_)                 // 8 chunks per row
#define NBLK (B_*H_*NCH_)             // 2048 blocks

// ---------------------------------------------------------------------------
// Kernel 1: fold W0 + BN + W1 into Weff[4][256] + beff[4].
// ---------------------------------------------------------------------------
__global__ __launch_bounds__(256) void prep_kernel(
    const float* __restrict__ W0, const float* __restrict__ b0,
    const float* __restrict__ gamma, const float* __restrict__ beta,
    const float* __restrict__ rmean, const float* __restrict__ rvar,
    const float* __restrict__ W1, const float* __restrict__ b1,
    float* __restrict__ Weff, float* __restrict__ beff)
{
    __shared__ float inv_s[C4_], shift_s[C4_], wg_s[G_][C4_];
    int t = threadIdx.x;
    if (t < C4_) {
        float inv = gamma[t] * rsqrtf(rvar[t] + 1e-5f);
        inv_s[t]   = inv;
        shift_s[t] = (b0[t] - rmean[t]) * inv + beta[t];
    }
    __syncthreads();
    if (t < G_ * C4_) wg_s[t >> 6][t & 63] = W1[t] * inv_s[t & 63];
    __syncthreads();
    float s0 = 0.f, s1 = 0.f, s2 = 0.f, s3 = 0.f;
    for (int o = 0; o < C4_; ++o) {
        float w0 = W0[o * C_ + t];
        s0 += wg_s[0][o] * w0;
        s1 += wg_s[1][o] * w0;
        s2 += wg_s[2][o] * w0;
        s3 += wg_s[3][o] * w0;
    }
    Weff[0*C_ + t] = s0;
    Weff[1*C_ + t] = s1;
    Weff[2*C_ + t] = s2;
    Weff[3*C_ + t] = s3;
    if (t < G_) {
        float s = b1[t];
        for (int o = 0; o < C4_; ++o) s += W1[t*C4_ + o] * shift_s[o];
        beff[t] = s;
    }
}

// ---------------------------------------------------------------------------
// Kernel 2: transpose x (B,C,HW) -> xT (B,HW,C).
// ---------------------------------------------------------------------------
__global__ __launch_bounds__(256) void transpose_kernel(
    const float* __restrict__ x, float* __restrict__ xT)
{
    __shared__ float tile[32][33];
    int tx = threadIdx.x, ty = threadIdx.y;
    int hw0 = blockIdx.x * 32, c0 = blockIdx.y * 32, b = blockIdx.z;
    const float* xb  = x  + (size_t)b * C_ * HW_;
    float*       xTb = xT + (size_t)b * C_ * HW_;
    #pragma unroll
    for (int j = 0; j < 4; ++j)
        tile[ty + 8*j][tx] = xb[(size_t)(c0 + ty + 8*j) * HW_ + hw0 + tx];
    __syncthreads();
    #pragma unroll
    for (int j = 0; j < 4; ++j)
        xTb[(size_t)(hw0 + ty + 8*j) * C_ + c0 + tx] = tile[tx][ty + 8*j];
}

// ---------------------------------------------------------------------------
// Kernel 3: deformable 3x3 unfold + bilinear + max + 4x256 dot + sigmoid.
// Block = 512 thr (8 waves) covers 16 consecutive pixels of one row; each
// wave owns 2 pixels -> grid 2048 (8 blocks/CU, 100% occupancy cap).
// Bijective XCD swizzle: 256 consecutive chunk-ids (= 32 rows) per XCD so
// the gather working set (~4 MB) fits the per-XCD L2.
// FUSED=1: writes the tiled (B,256,H,W) output directly (nontemporal).
// FUSED=0: writes att (B,4,H,W) to ws; expand_kernel tiles it.
// ---------------------------------------------------------------------------
template<int FUSED>
__global__ __launch_bounds__(512, 8) void main_kernel(
    const float* __restrict__ xT, const float* __restrict__ offset,
    const float* __restrict__ Weff, const float* __restrict__ beff,
    float* __restrict__ dst)
{
    __shared__ float offs_lds[18][PX_];
    __shared__ float att_lds[G_ * PX_];
    int t = threadIdx.x;
    int wave = t >> 6, lane = t & 63;

    // XCD-aware bijective swizzle (NBLK % 8 == 0)
    int bid = blockIdx.x;
    int lid = (bid & 7) * (NBLK / 8) + (bid >> 3);
    int xc = lid & (NCH_ - 1);
    int y  = (lid >> 3) & (H_ - 1);
    int b  = lid >> 10;               // lid / (NCH_*H_)
    int x0 = xc * PX_;
    int c0 = lane * 4;

    const float* xTb  = xT + (size_t)b * HW_ * C_;
    const float* offb = offset + (size_t)b * 18 * HW_ + (size_t)y * W_ + x0;

    if (t < 18 * PX_)
        offs_lds[t >> 4][t & 15] = offb[(size_t)(t >> 4) * HW_ + (t & 15)];

    float wf[G_][4];
    #pragma unroll
    for (int g = 0; g < G_; ++g) {
        float4 v = *(const float4*)(Weff + g*C_ + c0);
        wf[g][0] = v.x; wf[g][1] = v.y; wf[g][2] = v.z; wf[g][3] = v.w;
    }
    float be[G_];
    #pragma unroll
    for (int g = 0; g < G_; ++g) be[g] = beff[g];

    __syncthreads();

    #pragma unroll
    for (int i = 0; i < 2; ++i) {
        int px = wave * 2 + i;
        int x  = x0 + px;
        float fm0 = -3.4028235e38f, fm1 = fm0, fm2 = fm0, fm3 = fm0;

        #pragma unroll
        for (int k = 0; k < 9; ++k) {
            float oy = offs_lds[2*k    ][px];
            float ox = offs_lds[2*k + 1][px];
            float py = (float)(y + (k/3) - 1) + oy;
            float px_ = (float)(x + (k%3) - 1) + ox;
            float y0f = floorf(py), x0f = floorf(px_);
            float fy = py - y0f, fx = px_ - x0f;
            float vy0 = (y0f >=  0.f && y0f <= 127.f) ? 1.f : 0.f;
            float vy1 = (y0f >= -1.f && y0f <= 126.f) ? 1.f : 0.f;
            float vx0 = (x0f >=  0.f && x0f <= 127.f) ? 1.f : 0.f;
            float vx1 = (x0f >= -1.f && x0f <= 126.f) ? 1.f : 0.f;
            float wy0 = (1.f - fy) * vy0, wy1 = fy * vy1;
            float wx0 = (1.f - fx) * vx0, wx1 = fx * vx1;
            int iy0 = min(max((int)y0f,     0), H_-1);
            int iy1 = min(max((int)y0f + 1, 0), H_-1);
            int ix0 = min(max((int)x0f,     0), W_-1);
            int ix1 = min(max((int)x0f + 1, 0), W_-1);
            const float4 v00 = *(const float4*)(xTb + (((size_t)iy0*W_ + ix0) << 8) + c0);
            const float4 v01 = *(const float4*)(xTb + (((size_t)iy0*W_ + ix1) << 8) + c0);
            const float4 v10 = *(const float4*)(xTb + (((size_t)iy1*W_ + ix0) << 8) + c0);
            const float4 v11 = *(const float4*)(xTb + (((size_t)iy1*W_ + ix1) << 8) + c0);
            float w00 = wy0*wx0, w01 = wy0*wx1, w10 = wy1*wx0, w11 = wy1*wx1;
            float a0 = w00*v00.x + w01*v01.x + w10*v10.x + w11*v11.x;
            float a1 = w00*v00.y + w01*v01.y + w10*v10.y + w11*v11.y;
            float a2 = w00*v00.z + w01*v01.z + w10*v10.z + w11*v11.z;
            float a3 = w00*v00.w + w01*v01.w + w10*v10.w + w11*v11.w;
            fm0 = fmaxf(fm0, a0);
            fm1 = fmaxf(fm1, a1);
            fm2 = fmaxf(fm2, a2);
            fm3 = fmaxf(fm3, a3);
        }

        float p[G_];
        #pragma unroll
        for (int g = 0; g < G_; ++g)
            p[g] = wf[g][0]*fm0 + wf[g][1]*fm1 + wf[g][2]*fm2 + wf[g][3]*fm3;

        #pragma unroll
        for (int off2 = 32; off2 > 0; off2 >>= 1) {
            #pragma unroll
            for (int g = 0; g < G_; ++g)
                p[g] += __shfl_xor(p[g], off2);
        }

        if (lane == 0) {
            #pragma unroll
            for (int g = 0; g < G_; ++g)
                att_lds[g*PX_ + px] = 1.f / (1.f + expf(-(p[g] + be[g])));
        }
    }
    __syncthreads();

    if (FUSED) {
        // write the tiled output directly: out[b][c][y][x0..x0+15], c tiled by 4
        int px = t & 15, cb = t >> 4;       // cb in [0,32)
        float* ob = dst + (size_t)b * C_ * HW_ + (size_t)y * W_ + x0;
        #pragma unroll
        for (int cc = 0; cc < 8; ++cc) {
            int c = cb + cc * 32;
            __builtin_nontemporal_store(att_lds[(c & 3) * PX_ + px],
                                        ob + (size_t)c * HW_ + px);
        }
    } else {
        if (t < G_ * PX_) {
            int g = t >> 4, px = t & 15;
            dst[(size_t)(b*G_ + g) * HW_ + (size_t)y * W_ + x0 + px] = att_lds[t];
        }
    }
}

// ---------------------------------------------------------------------------
// Kernel 4 (fallback only): tile att (B,4,H,W) -> out (B,256,H,W).
// ---------------------------------------------------------------------------
__global__ __launch_bounds__(256) void expand_kernel(
    const float* __restrict__ att, float* __restrict__ out)
{
    int e4 = blockIdx.x * 256 + threadIdx.x;
    int x4 = e4 & 31;
    int y  = (e4 >> 5) & (H_ - 1);
    int c  = (e4 >> 12) & (C_ - 1);
    int b  = (e4 >> 20) & 1;
    float4 v = *(const float4*)(att + ((size_t)(b*G_ + (c & 3)) * HW_) + y*W_ + x4*4);
    *(float4*)(out + ((size_t)(b*C_ + c) * HW_) + y*W_ + x4*4) = v;
}

// ---------------------------------------------------------------------------
extern "C" void kernel_launch(void* const* d_in, const int* in_sizes, int n_in,
                              void* d_out, int out_size, void* d_ws, size_t ws_size,
                              hipStream_t stream)
{
    (void)in_sizes; (void)n_in; (void)out_size;
    const float* x      = (const float*)d_in[0];
    const float* offset = (const float*)d_in[1];
    const float* W0     = (const float*)d_in[2];
    const float* b0     = (const float*)d_in[3];
    const float* gamma  = (const float*)d_in[4];
    const float* beta   = (const float*)d_in[5];
    const float* rmean  = (const float*)d_in[6];
    const float* rvar   = (const float*)d_in[7];
    const float* W1     = (const float*)d_in[8];
    const float* b1     = (const float*)d_in[9];
    float* out = (float*)d_out;

    const size_t xT_elems = (size_t)B_ * C_ * HW_;            // 8.4M floats
    const size_t need_fused = (xT_elems + G_*C_ + G_ + 64) * sizeof(float);

    if (ws_size >= need_fused) {
        // fused path: xT in ws, main writes d_out directly
        float* xT   = (float*)d_ws;
        float* Weff = xT + xT_elems;
        float* beff = Weff + G_ * C_;
        prep_kernel<<<dim3(1), dim3(256), 0, stream>>>(
            W0, b0, gamma, beta, rmean, rvar, W1, b1, Weff, beff);
        transpose_kernel<<<dim3(HW_/32, C_/32, B_), dim3(32, 8), 0, stream>>>(x, xT);
        main_kernel<1><<<dim3(NBLK), dim3(512), 0, stream>>>(
            xT, offset, Weff, beff, out);
    } else {
        // fallback: xT in d_out, att in ws, separate expand
        float* xT   = out;
        float* att  = (float*)d_ws;
        float* Weff = att + (size_t)B_ * G_ * HW_;
        float* beff = Weff + G_ * C_;
        prep_kernel<<<dim3(1), dim3(256), 0, stream>>>(
            W0, b0, gamma, beta, rmean, rvar, W1, b1, Weff, beff);
        transpose_kernel<<<dim3(HW_/32, C_/32, B_), dim3(32, 8), 0, stream>>>(x, xT);
        main_kernel<0><<<dim3(NBLK), dim3(512), 0, stream>>>(
            xT, offset, Weff, beff, att);
        expand_kernel<<<dim3((B_*C_*HW_/4) / 256), dim3(256), 0, stream>>>(att, out);
    }
}

// Round 5
// 148.781 us; speedup vs baseline: 1.7035x; 1.1491x over previous
//
#include <hip/hip_runtime.h>
#include <math.h>

#define B_   2
#define C_   256
#define C4_  64
#define H_   128
#define W_   128
#define HW_  (H_*W_)
#define G_   4
#define PX_  32                       // pixels per main block
#define NCH_ (W_/PX_)                 // 4 chunks per row
#define NBLK (B_*H_*NCH_)             // 1024 blocks

typedef float f4_t __attribute__((ext_vector_type(4)));

// ---------------------------------------------------------------------------
// prep body: fold W0 + BN + W1 into Weff[4][256] + beff[4].  Run by one
// 256-thread block (called from the transpose kernel's z==B_ slab).
// ---------------------------------------------------------------------------
__device__ void prep_body(
    const float* __restrict__ W0, const float* __restrict__ b0,
    const float* __restrict__ gamma, const float* __restrict__ beta,
    const float* __restrict__ rmean, const float* __restrict__ rvar,
    const float* __restrict__ W1, const float* __restrict__ b1,
    float* __restrict__ Weff, float* __restrict__ beff)
{
    __shared__ float inv_s[C4_], shift_s[C4_], wg_s[G_][C4_];
    int t = threadIdx.x;
    if (t < C4_) {
        float inv = gamma[t] * rsqrtf(rvar[t] + 1e-5f);
        inv_s[t]   = inv;
        shift_s[t] = (b0[t] - rmean[t]) * inv + beta[t];
    }
    __syncthreads();
    if (t < G_ * C4_) wg_s[t >> 6][t & 63] = W1[t] * inv_s[t & 63];
    __syncthreads();
    float s0 = 0.f, s1 = 0.f, s2 = 0.f, s3 = 0.f;
    for (int o = 0; o < C4_; ++o) {
        float w0 = W0[o * C_ + t];
        s0 += wg_s[0][o] * w0;
        s1 += wg_s[1][o] * w0;
        s2 += wg_s[2][o] * w0;
        s3 += wg_s[3][o] * w0;
    }
    Weff[0*C_ + t] = s0;
    Weff[1*C_ + t] = s1;
    Weff[2*C_ + t] = s2;
    Weff[3*C_ + t] = s3;
    if (t < G_) {
        float s = b1[t];
        for (int o = 0; o < C4_; ++o) s += W1[t*C4_ + o] * shift_s[o];
        beff[t] = s;
    }
}

// ---------------------------------------------------------------------------
// Transpose x (B,C,HW) -> xT (B,HW,C), LDS-free, float4 both sides via 4x4
// register transpose.  Per block: 32 c x 128 hw tile, 256 threads.
// grid.z == B_ slab: block (0,0) additionally runs prep (others no-op).
// ---------------------------------------------------------------------------
__global__ __launch_bounds__(256) void transpose_kernel(
    const float* __restrict__ x, float* __restrict__ xT,
    const float* __restrict__ W0, const float* __restrict__ b0,
    const float* __restrict__ gamma, const float* __restrict__ beta,
    const float* __restrict__ rmean, const float* __restrict__ rvar,
    const float* __restrict__ W1, const float* __restrict__ b1,
    float* __restrict__ Weff, float* __restrict__ beff)
{
    if (blockIdx.z == B_) {
        if (blockIdx.x == 0 && blockIdx.y == 0)
            prep_body(W0, b0, gamma, beta, rmean, rvar, W1, b1, Weff, beff);
        return;
    }
    int t = threadIdx.x;
    int cq  = t & 7;        // 8 c-quads -> 32 channels
    int hw4 = t >> 3;       // 32 hw-quads -> 128 positions
    int hw0 = blockIdx.x * 128, c0 = blockIdx.y * 32, b = blockIdx.z;

    const float* xb = x + (size_t)b * C_ * HW_ + (size_t)(c0 + cq*4) * HW_ + hw0 + hw4*4;
    float4 r0 = *(const float4*)(xb);
    float4 r1 = *(const float4*)(xb +     HW_);
    float4 r2 = *(const float4*)(xb + 2 * HW_);
    float4 r3 = *(const float4*)(xb + 3 * HW_);

    float4 t0 = {r0.x, r1.x, r2.x, r3.x};
    float4 t1 = {r0.y, r1.y, r2.y, r3.y};
    float4 t2 = {r0.z, r1.z, r2.z, r3.z};
    float4 t3 = {r0.w, r1.w, r2.w, r3.w};

    float* xTb = xT + (size_t)b * HW_ * C_ + (size_t)(hw0 + hw4*4) * C_ + c0 + cq*4;
    *(float4*)(xTb)          = t0;
    *(float4*)(xTb +     C_) = t1;
    *(float4*)(xTb + 2 * C_) = t2;
    *(float4*)(xTb + 3 * C_) = t3;
}

// ---------------------------------------------------------------------------
// Main: deformable 3x3 unfold + bilinear + max + 4x256 dot + sigmoid.
// Phase 1: 288 threads compute tap weights + corner byte-offsets for the
//          block's 32 pixels (vectorized across lanes), stash in LDS.
// Phase 2: 8 waves x 4 pixels; per tap: 2 LDS broadcast reads, 4 float4
//          gathers, 16 FMA + 4 max.  Lane l owns channels [4l,4l+4).
// FUSED=1 writes the tiled (B,256,H,W) output directly (full 128B lines).
// ---------------------------------------------------------------------------
template<int FUSED>
__global__ __launch_bounds__(512, 8) void main_kernel(
    const float* __restrict__ xT, const float* __restrict__ offset,
    const float* __restrict__ Weff, const float* __restrict__ beff,
    float* __restrict__ dst)
{
    __shared__ float    wgt_lds[9][PX_][4];
    __shared__ unsigned adr_lds[9][PX_][4];
    __shared__ float    att_lds[G_][PX_];

    int t = threadIdx.x;
    int wave = t >> 6, lane = t & 63;

    // bijective XCD swizzle (NBLK % 8 == 0): 128 consecutive lids per XCD
    int bid = blockIdx.x;
    int lid = (bid & 7) * (NBLK / 8) + (bid >> 3);
    int xc = lid & (NCH_ - 1);
    int y  = (lid >> 2) & (H_ - 1);
    int b  = lid >> 9;
    int x0 = xc * PX_;
    int c0 = lane * 4;

    const float* xTb = xT + (size_t)b * HW_ * C_;

    // ---- phase 1: per-tap parameters, vectorized across threads ----
    if (t < 9 * PX_) {
        int k  = t >> 5, px = t & 31;
        int x  = x0 + px;
        const float* offb = offset + (size_t)b * 18 * HW_ + (size_t)y * W_;
        float oy = offb[(size_t)(2*k    ) * HW_ + x];
        float ox = offb[(size_t)(2*k + 1) * HW_ + x];
        float py = (float)(y + (k/3) - 1) + oy;
        float qx = (float)(x + (k%3) - 1) + ox;
        float y0f = floorf(py), x0f = floorf(qx);
        float fy = py - y0f, fx = qx - x0f;
        float vy0 = (y0f >=  0.f && y0f <= 127.f) ? 1.f : 0.f;
        float vy1 = (y0f >= -1.f && y0f <= 126.f) ? 1.f : 0.f;
        float vx0 = (x0f >=  0.f && x0f <= 127.f) ? 1.f : 0.f;
        float vx1 = (x0f >= -1.f && x0f <= 126.f) ? 1.f : 0.f;
        float wy0 = (1.f - fy) * vy0, wy1 = fy * vy1;
        float wx0 = (1.f - fx) * vx0, wx1 = fx * vx1;
        int iy0 = min(max((int)y0f,     0), H_-1);
        int iy1 = min(max((int)y0f + 1, 0), H_-1);
        int ix0 = min(max((int)x0f,     0), W_-1);
        int ix1 = min(max((int)x0f + 1, 0), W_-1);
        float4 wg = {wy0*wx0, wy0*wx1, wy1*wx0, wy1*wx1};
        uint4  ad = {(unsigned)((iy0*W_ + ix0) << 10),
                     (unsigned)((iy0*W_ + ix1) << 10),
                     (unsigned)((iy1*W_ + ix0) << 10),
                     (unsigned)((iy1*W_ + ix1) << 10)};
        *(float4*)(&wgt_lds[k][px][0]) = wg;
        *(uint4* )(&adr_lds[k][px][0]) = ad;
    }

    // per-lane Weff fragment + beff (independent of phase 1)
    float wf[G_][4];
    #pragma unroll
    for (int g = 0; g < G_; ++g) {
        float4 v = *(const float4*)(Weff + g*C_ + c0);
        wf[g][0] = v.x; wf[g][1] = v.y; wf[g][2] = v.z; wf[g][3] = v.w;
    }
    float be[G_];
    #pragma unroll
    for (int g = 0; g < G_; ++g) be[g] = beff[g];

    __syncthreads();

    // ---- phase 2: gathers + bilinear + max + projection ----
    const char* xTc = (const char*)xTb;
    int laneoff = lane << 4;            // c0 * 4 bytes

    #pragma unroll
    for (int i = 0; i < 4; ++i) {
        int px = wave * 4 + i;
        float fm0 = -3.4028235e38f, fm1 = fm0, fm2 = fm0, fm3 = fm0;

        #pragma unroll
        for (int k = 0; k < 9; ++k) {
            float4 wg = *(const float4*)(&wgt_lds[k][px][0]);
            uint4  ad = *(const uint4* )(&adr_lds[k][px][0]);
            const float4 v00 = *(const float4*)(xTc + ad.x + laneoff);
            const float4 v01 = *(const float4*)(xTc + ad.y + laneoff);
            const float4 v10 = *(const float4*)(xTc + ad.z + laneoff);
            const float4 v11 = *(const float4*)(xTc + ad.w + laneoff);
            float a0 = wg.x*v00.x + wg.y*v01.x + wg.z*v10.x + wg.w*v11.x;
            float a1 = wg.x*v00.y + wg.y*v01.y + wg.z*v10.y + wg.w*v11.y;
            float a2 = wg.x*v00.z + wg.y*v01.z + wg.z*v10.z + wg.w*v11.z;
            float a3 = wg.x*v00.w + wg.y*v01.w + wg.z*v10.w + wg.w*v11.w;
            fm0 = fmaxf(fm0, a0);
            fm1 = fmaxf(fm1, a1);
            fm2 = fmaxf(fm2, a2);
            fm3 = fmaxf(fm3, a3);
        }

        float p[G_];
        #pragma unroll
        for (int g = 0; g < G_; ++g)
            p[g] = wf[g][0]*fm0 + wf[g][1]*fm1 + wf[g][2]*fm2 + wf[g][3]*fm3;

        #pragma unroll
        for (int off2 = 32; off2 > 0; off2 >>= 1) {
            #pragma unroll
            for (int g = 0; g < G_; ++g)
                p[g] += __shfl_xor(p[g], off2);
        }

        if (lane == 0) {
            #pragma unroll
            for (int g = 0; g < G_; ++g)
                att_lds[g][px] = 1.f / (1.f + expf(-(p[g] + be[g])));
        }
    }
    __syncthreads();

    if (FUSED) {
        // tiled output: out[b][c][y][x0..x0+31]; 128B (full line) per channel
        float* ob = dst + (size_t)b * C_ * HW_ + (size_t)y * W_ + x0;
        #pragma unroll
        for (int rep = 0; rep < 4; ++rep) {
            int idx = rep * 512 + t;        // float4 slot over 256 ch x 8 quads
            int c   = idx >> 3;
            int x4  = idx & 7;
            f4_t v = *(const f4_t*)(&att_lds[c & 3][x4 * 4]);
            __builtin_nontemporal_store(v, (f4_t*)(ob + (size_t)c * HW_ + x4 * 4));
        }
    } else {
        if (t < G_ * PX_) {
            int g = t >> 5, px = t & 31;
            dst[(size_t)(b*G_ + g) * HW_ + (size_t)y * W_ + x0 + px] = att_lds[g][px];
        }
    }
}

// ---------------------------------------------------------------------------
// Fallback only: tile att (B,4,H,W) -> out (B,256,H,W).
// ---------------------------------------------------------------------------
__global__ __launch_bounds__(256) void expand_kernel(
    const float* __restrict__ att, float* __restrict__ out)
{
    int e4 = blockIdx.x * 256 + threadIdx.x;
    int x4 = e4 & 31;
    int y  = (e4 >> 5) & (H_ - 1);
    int c  = (e4 >> 12) & (C_ - 1);
    int b  = (e4 >> 20) & 1;
    float4 v = *(const float4*)(att + ((size_t)(b*G_ + (c & 3)) * HW_) + y*W_ + x4*4);
    *(float4*)(out + ((size_t)(b*C_ + c) * HW_) + y*W_ + x4*4) = v;
}

// ---------------------------------------------------------------------------
extern "C" void kernel_launch(void* const* d_in, const int* in_sizes, int n_in,
                              void* d_out, int out_size, void* d_ws, size_t ws_size,
                              hipStream_t stream)
{
    (void)in_sizes; (void)n_in; (void)out_size;
    const float* x      = (const float*)d_in[0];
    const float* offset = (const float*)d_in[1];
    const float* W0     = (const float*)d_in[2];
    const float* b0     = (const float*)d_in[3];
    const float* gamma  = (const float*)d_in[4];
    const float* beta   = (const float*)d_in[5];
    const float* rmean  = (const float*)d_in[6];
    const float* rvar   = (const float*)d_in[7];
    const float* W1     = (const float*)d_in[8];
    const float* b1     = (const float*)d_in[9];
    float* out = (float*)d_out;

    const size_t xT_elems = (size_t)B_ * C_ * HW_;
    const size_t need_fused = (xT_elems + G_*C_ + G_ + 64) * sizeof(float);

    if (ws_size >= need_fused) {
        float* xT   = (float*)d_ws;
        float* Weff = xT + xT_elems;
        float* beff = Weff + G_ * C_;
        transpose_kernel<<<dim3(HW_/128, C_/32, B_ + 1), dim3(256), 0, stream>>>(
            x, xT, W0, b0, gamma, beta, rmean, rvar, W1, b1, Weff, beff);
        main_kernel<1><<<dim3(NBLK), dim3(512), 0, stream>>>(
            xT, offset, Weff, beff, out);
    } else {
        float* xT   = out;
        float* att  = (float*)d_ws;
        float* Weff = att + (size_t)B_ * G_ * HW_;
        float* beff = Weff + G_ * C_;
        transpose_kernel<<<dim3(HW_/128, C_/32, B_ + 1), dim3(256), 0, stream>>>(
            x, xT, W0, b0, gamma, beta, rmean, rvar, W1, b1, Weff, beff);
        main_kernel<0><<<dim3(NBLK), dim3(512), 0, stream>>>(
            xT, offset, Weff, beff, att);
        expand_kernel<<<dim3((B_*C_*HW_/4) / 256), dim3(256), 0, stream>>>(att, out);
    }
}